// Round 13
// baseline (295.556 us; speedup 1.0000x reference)
//
#include <hip/hip_runtime.h>
#include <math.h>

#define NUM_E   1024
#define ZQ_ELEM 8388608         // 32*64*64*64
#define AGRID   1024

typedef short bf16x8 __attribute__((ext_vector_type(8)));
typedef float f32x16 __attribute__((ext_vector_type(16)));

__device__ inline unsigned short rne_bf16(float v) {
    unsigned u = __float_as_uint(v);
    return (unsigned short)((u + 0x7FFFu + ((u >> 16) & 1u)) >> 16);  // RNE, finite-safe
}
// monotone float->u32 map (total order preserving)
__device__ inline unsigned fmap(float s) {
    unsigned b = __float_as_uint(s);
    return b ^ (unsigned)(((int)b >> 31) | 0x80000000);
}
__device__ inline float funmap(unsigned u) {
    unsigned mask = (unsigned)(((int)(~u) >> 31)) | 0x80000000u;
    return __uint_as_float(u ^ mask);
}

// ---------------------------------------------------------------- prep: ee + bf16 hi/lo B fragments
// B-frag layout for mfma_f32_32x32x16_bf16: lane l holds col j = nt*32+(l&31),
// k = kt*16 + (l>>5)*8 + i.  Packet index = (nt*4+kt)*64 + (l>>5)*32 + (j&31).
__global__ __launch_bounds__(256) void vq_prep(const float* __restrict__ cb,
                                               float* __restrict__ ee,
                                               unsigned short* __restrict__ ehi,
                                               unsigned short* __restrict__ elo)
{
    int j = blockIdx.x * 256 + threadIdx.x;   // grid 4 -> 1024 codes
    const float* r = cb + (size_t)j * 64;
    float v[64];
#pragma unroll
    for (int k = 0; k < 64; ++k) v[k] = r[k];
    float a = 0.f;
#pragma unroll
    for (int k = 0; k < 64; ++k) a = fmaf(v[k], v[k], a);   // same chain as r1-r12
    ee[j] = a;

    int nt = j >> 5, jc = j & 31;
#pragma unroll
    for (int kt = 0; kt < 4; ++kt)
#pragma unroll
        for (int h = 0; h < 2; ++h) {
            bf16x8 vh, vl;
#pragma unroll
            for (int i = 0; i < 8; ++i) {
                float x = v[kt * 16 + h * 8 + i];
                unsigned short hb = rne_bf16(x);
                float hf = __uint_as_float((unsigned)hb << 16);
                vh[i] = (short)hb;
                vl[i] = (short)rne_bf16(x - hf);
            }
            size_t pkt = ((size_t)(nt * 4 + kt) * 64 + h * 32 + jc) * 8;
            *(bf16x8*)(ehi + pkt) = vh;
            *(bf16x8*)(elo + pkt) = vl;
        }
}

// exact d for (point pl, code j), z from global, batched; chain bit-identical to r1-r12
__device__ inline unsigned long long key_glob(const float* zb, float zz, float eej,
                                              const float* cb, int pl, int j)
{
    const float4* cr = (const float4*)(cb + ((size_t)j << 6));
    float a = 0.f;
#pragma unroll
    for (int qb = 0; qb < 4; ++qb) {
        float4 c0 = cr[qb * 4 + 0];
        float4 c1 = cr[qb * 4 + 1];
        float4 c2 = cr[qb * 4 + 2];
        float4 c3 = cr[qb * 4 + 3];
        float t[16];
#pragma unroll
        for (int i = 0; i < 16; ++i)
            t[i] = zb[(size_t)(qb * 16 + i) * 4096 + pl];
        a = fmaf(t[0],  c0.x, a); a = fmaf(t[1],  c0.y, a);
        a = fmaf(t[2],  c0.z, a); a = fmaf(t[3],  c0.w, a);
        a = fmaf(t[4],  c1.x, a); a = fmaf(t[5],  c1.y, a);
        a = fmaf(t[6],  c1.z, a); a = fmaf(t[7],  c1.w, a);
        a = fmaf(t[8],  c2.x, a); a = fmaf(t[9],  c2.y, a);
        a = fmaf(t[10], c2.z, a); a = fmaf(t[11], c2.w, a);
        a = fmaf(t[12], c3.x, a); a = fmaf(t[13], c3.y, a);
        a = fmaf(t[14], c3.z, a); a = fmaf(t[15], c3.w, a);
    }
    float t1 = zz + eej;
    float d  = fmaf(-2.f, a, t1);
    return ((unsigned long long)__float_as_uint(d) << 32) | (unsigned long long)j;
}

// ---------------------------------------------------------------- argmin + quant
// SINGLE sweep, 3-MFMA accurate filter, in-loop top-2+index tracking.
// Block = 256 threads = 4 waves = 128 points; wave wv owns rows wv*32..wv*32+31.
__global__ __launch_bounds__(256, 3) void vq_argmin(
    const float* __restrict__ z, const float* __restrict__ cb,
    const unsigned short* __restrict__ ehi, const unsigned short* __restrict__ elo,
    const float* __restrict__ ee,
    float* __restrict__ idx_f, int* __restrict__ counts,
    float* __restrict__ zq, double* __restrict__ partials)
{
    __shared__ float zzs[128];
    __shared__ float wp[128];
    __shared__ int   ibuf[128];
    __shared__ unsigned long long best64[128];
    __shared__ int   queue[128];
    __shared__ unsigned int qcnt;
    __shared__ double wsum[4];

    const int tid  = threadIdx.x;
    const int g    = blockIdx.x;               // 1024 blocks: (b, h-pair)
    const int lane = tid & 63, wv = tid >> 6;
    const size_t zoff = ((size_t)(g >> 5) << 18) + (size_t)((g & 31) << 7);
    const float* zb = z + zoff;
    const bf16x8* eh8 = (const bf16x8*)ehi;
    const bf16x8* el8 = (const bf16x8*)elo;

    if (tid < 128) best64[tid] = 0xFFFFFFFFFFFFFFFFull;
    if (tid == 0) qcnt = 0;

    // ---- zz: exact 64-chain fmaf order (r1-r12), loads batched 16-wide
    if (tid < 128) {
        float a = 0.f;
#pragma unroll
        for (int kb = 0; kb < 4; ++kb) {
            float t[16];
#pragma unroll
            for (int i = 0; i < 16; ++i)
                t[i] = zb[(size_t)(kb * 16 + i) * 4096 + tid];
#pragma unroll
            for (int i = 0; i < 16; ++i) a = fmaf(t[i], t[i], a);
        }
        zzs[tid] = a;
    }

    // ---- A-fragments (z hi/lo) + per-point TIGHT window (3-MFMA residual bound)
    bf16x8 ah[4], al[4];
    {
        int h = lane >> 5;
        int pl = wv * 32 + (lane & 31);
        float s1 = 0.f, sd = 0.f;
#pragma unroll
        for (int kt = 0; kt < 4; ++kt) {
            float t[8];
#pragma unroll
            for (int i = 0; i < 8; ++i)
                t[i] = zb[(size_t)(kt * 16 + h * 8 + i) * 4096 + pl];
#pragma unroll
            for (int i = 0; i < 8; ++i) {
                float x = t[i];
                unsigned short hb = rne_bf16(x);
                float hf = __uint_as_float((unsigned)hb << 16);
                ah[kt][i] = (short)hb;
                al[kt][i] = (short)rne_bf16(x - hf);
                s1 += fabsf(x);
                sd += fabsf(x - hf);
            }
        }
        s1 += __shfl_xor(s1, 32);
        sd += __shfl_xor(sd, 32);
        // 3-MFMA residual: split terms sd*2^-18-scale + s1*2^-27-scale, 4x slack,
        // + 8e-5 for pairwise offset/accum roundings (>=4x the 2.1e-5 bound)
        if (lane < 32) wp[pl] = 4.f * (sd * 6e-6f + s1 * 3e-8f) + 8e-5f;
    }
    __syncthreads();

    // ---- single sweep: top-2 (+ index of min) per row, mapped-u32 domain
    unsigned m1u[16], m2u[16];
    int      n1[16];
#pragma unroll
    for (int r = 0; r < 16; ++r) { m1u[r] = 0xFFFFFFFFu; m2u[r] = 0xFFFFFFFFu; n1[r] = 0; }

#pragma unroll 1
    for (int nt = 0; nt < 32; ++nt) {
        bf16x8 bh[4], bl[4];
        int base = nt * 256 + lane;
#pragma unroll
        for (int kt = 0; kt < 4; ++kt) {
            bh[kt] = eh8[base + kt * 64];
            bl[kt] = el8[base + kt * 64];
        }
        float eej = ee[nt * 32 + (lane & 31)];
        f32x16 acc;
#pragma unroll
        for (int r = 0; r < 16; ++r) acc[r] = 0.f;
#pragma unroll
        for (int kt = 0; kt < 4; ++kt) {
            acc = __builtin_amdgcn_mfma_f32_32x32x16_bf16(ah[kt], bh[kt], acc, 0, 0, 0);
            acc = __builtin_amdgcn_mfma_f32_32x32x16_bf16(ah[kt], bl[kt], acc, 0, 0, 0);
            acc = __builtin_amdgcn_mfma_f32_32x32x16_bf16(al[kt], bh[kt], acc, 0, 0, 0);
        }
#pragma unroll
        for (int r = 0; r < 16; ++r) {
            float s = fmaf(-2.f, acc[r], eej);
            unsigned u = fmap(s);
            bool lt = u < m1u[r];
            m2u[r] = min(m2u[r], lt ? m1u[r] : u);   // equal u -> m2==m1 -> ambiguous
            m1u[r] = lt ? u : m1u[r];
            n1[r]  = lt ? nt : n1[r];
        }
    }

    // ---- butterfly top-2 merge across the 32 col-lanes (lowest idx on equal value)
    int i1[16];
#pragma unroll
    for (int r = 0; r < 16; ++r) i1[r] = n1[r] * 32 + (lane & 31);
#pragma unroll
    for (int r = 0; r < 16; ++r) {
#pragma unroll
        for (int d2 = 1; d2 <= 16; d2 <<= 1) {
            unsigned pu  = __shfl_xor(m1u[r], d2);
            int      pi  = __shfl_xor(i1[r],  d2);
            unsigned pm2 = __shfl_xor(m2u[r], d2);
            unsigned nm2 = min(min(m2u[r], pm2), max(m1u[r], pu));
            bool take = (pu < m1u[r]) || (pu == m1u[r] && pi < i1[r]);
            i1[r]  = take ? pi : i1[r];
            m1u[r] = min(m1u[r], pu);
            m2u[r] = nm2;
        }
    }

    // ---- decide fast/ambiguous per row (writer lanes: lane&31 == 0)
    if ((lane & 31) == 0) {
#pragma unroll
        for (int r = 0; r < 16; ++r) {
            int pl = wv * 32 + 4 * (lane >> 5) + (r & 3) + 8 * (r >> 2);
            float s1v = funmap(m1u[r]);
            float s2v = funmap(m2u[r]);
            if (s2v - s1v > wp[pl]) {
                ibuf[pl] = i1[r];                      // unique exact argmin, proven
            } else {
                ibuf[pl] = -1;
                queue[atomicAdd(&qcnt, 1u)] = pl;      // rare (~4%)
            }
        }
    }
    __syncthreads();

    // ---- slow path: full exact scan for ambiguous points (bit-identical formula)
    {
        int nq = (int)qcnt;
        for (int e = 0; e < nq; ++e) {
            int pl = queue[e];
            float zzp = zzs[pl];
            unsigned long long bk = 0xFFFFFFFFFFFFFFFFull;
#pragma unroll
            for (int s = 0; s < 4; ++s) {
                int j = tid + s * 256;
                unsigned long long k2 = key_glob(zb, zzp, ee[j], cb, pl, j);
                if (k2 < bk) bk = k2;
            }
            atomicMin(&best64[pl], bk);
        }
    }
    __syncthreads();
    if (tid < 128) {
        int bi = ibuf[tid];
        if (bi < 0) { bi = (int)(best64[tid] & 0xFFFFFFFFull); ibuf[tid] = bi; }
        idx_f[(size_t)g * 128 + tid] = (float)bi;
        atomicAdd(&counts[bi], 1);
    }
    __syncthreads();

    // ---- fused tail: z_q_st = fl(z + fl(q - z)); preloaded z float4s, float4 stores
    {
        int w4 = tid & 31, c8 = (tid >> 5) * 8;
        const float4* zb4 = (const float4*)zb;
        float4* zq4 = (float4*)(zq + zoff);
        size_t b0 = (size_t)ibuf[w4 * 4 + 0] << 6;
        size_t b1 = (size_t)ibuf[w4 * 4 + 1] << 6;
        size_t b2 = (size_t)ibuf[w4 * 4 + 2] << 6;
        size_t b3 = (size_t)ibuf[w4 * 4 + 3] << 6;
        float4 zv[8];
#pragma unroll
        for (int i = 0; i < 8; ++i) zv[i] = zb4[(size_t)(c8 + i) * 1024 + w4];
        double ls = 0.0;
#pragma unroll
        for (int i = 0; i < 8; ++i) {
            int c = c8 + i;
            float q0 = cb[b0 + c], q1 = cb[b1 + c], q2 = cb[b2 + c], q3 = cb[b3 + c];
            float t0 = q0 - zv[i].x, t1 = q1 - zv[i].y, t2 = q2 - zv[i].z, t3 = q3 - zv[i].w;
            zq4[(size_t)c * 1024 + w4] =
                make_float4(zv[i].x + t0, zv[i].y + t1, zv[i].z + t2, zv[i].w + t3);
            ls += (double)t0 * t0 + (double)t1 * t1 + (double)t2 * t2 + (double)t3 * t3;
        }
#pragma unroll
        for (int off = 32; off > 0; off >>= 1) ls += __shfl_down(ls, off);
        if ((tid & 63) == 0) wsum[tid >> 6] = ls;
    }
    __syncthreads();
    if (tid == 0) partials[g] = wsum[0] + wsum[1] + wsum[2] + wsum[3];
}

// ---------------------------------------------------------------- scalars
__global__ __launch_bounds__(256) void vq_final(
    const int* __restrict__ counts, const double* __restrict__ partials,
    float* __restrict__ scalars)
{
    __shared__ double sh[256];
    __shared__ double sl[256];
    int t = threadIdx.x;
    double s = 0.0;
    for (int j = t; j < NUM_E; j += 256) {
        float em   = (float)counts[j] * (1.0f / 131072.0f);
        float term = em * logf(em + 1e-10f);
        s += (double)term;
    }
    double l = 0.0;
#pragma unroll
    for (int j = 0; j < AGRID / 256; ++j) l += partials[j * 256 + t];
    sh[t] = s;
    sl[t] = l;
    __syncthreads();
    for (int off = 128; off > 0; off >>= 1) {
        if (t < off) { sh[t] += sh[t + off]; sl[t] += sl[t + off]; }
        __syncthreads();
    }
    if (t == 0) {
        float mm = (float)(sl[0] / 8388608.0);
        scalars[0] = mm + 0.5f * mm;         // mean1 + BETA*mean2
        scalars[1] = expf(-(float)sh[0]);    // perplexity
    }
}

// ---------------------------------------------------------------- launch
extern "C" void kernel_launch(void* const* d_in, const int* in_sizes, int n_in,
                              void* d_out, int out_size, void* d_ws, size_t ws_size,
                              hipStream_t stream)
{
    const float* z  = (const float*)d_in[0];
    const float* cb = (const float*)d_in[1];
    float* out     = (float*)d_out;
    float* zq      = out;                    // [32,64,64,64]
    float* scalars = out + ZQ_ELEM;          // loss, perplexity
    float* idx_f   = out + ZQ_ELEM + 2;      // [32,64,64] as float

    int*            counts   = (int*)d_ws;                               // 4 KB
    double*         partials = (double*)((char*)d_ws + 4096);            // 8 KB
    float*          ee       = (float*)((char*)d_ws + 12288);            // 4 KB
    unsigned short* ehi      = (unsigned short*)((char*)d_ws + 16384);   // 128 KB
    unsigned short* elo      = (unsigned short*)((char*)d_ws + 147456);  // 128 KB

    hipMemsetAsync(d_ws, 0, 4096, stream);                    // zero counts
    vq_prep  <<<4,     256, 0, stream>>>(cb, ee, ehi, elo);
    vq_argmin<<<AGRID, 256, 0, stream>>>(z, cb, ehi, elo, ee, idx_f, counts, zq, partials);
    vq_final <<<1,     256, 0, stream>>>(counts, partials, scalars);
}